// Round 2
// baseline (3285.770 us; speedup 1.0000x reference)
//
#include <hip/hip_runtime.h>
#include <cstdint>

// Cortex reservoir: embed(perm-gather) -> 512-step spiking scan -> dense readout.
// ws layout (73 MiB total):
//   OFF_PERM : perm int[1024]
//   OFF_V    : V ping-pong float[2][65536]
//   OFF_S    : S ping-pong float[2][65536]
//   OFF_A    : A chunk float[128][131072]   (V_t,S_t rows for the readout GEMM)
//   OFF_P    : split-K partials float[128][128][128]

namespace {

constexpr int TT = 512;
constexpr int DD = 256;
constexpr int CELLS = DD * DD;              // 65536
constexpr long KTOT = 2L * CELLS;           // 131072
constexpr int TB = 128;                     // time-chunk
constexpr int NCH = TT / TB;                // 4
constexpr int KSLAB = 1024;
constexpr int NSLAB = 128;                  // KTOT / KSLAB

constexpr long OFF_PERM = 0;
constexpr long OFF_V = 4096;
constexpr long OFF_S = OFF_V + 2L * CELLS * 4;
constexpr long OFF_A = OFF_S + 2L * CELLS * 4;
constexpr long OFF_P = OFF_A + (long)TB * KTOT * 4;
constexpr long WS_REQUIRED = OFF_P + (long)NSLAB * TB * 128 * 4;  // ~73 MiB

__global__ __launch_bounds__(256) void perm_kernel(const float* __restrict__ We,
                                                   int* __restrict__ perm) {
    int idx = blockIdx.x * 256 + threadIdx.x;       // over 1024*1024
    if (We[idx] > 0.5f) perm[idx >> 10] = idx & 1023;
}

// One reservoir step. 64 blocks x 256 threads; block = 4 rows x 256 cols.
// S counts are exact integers in fp32, so conv summation order is bit-irrelevant.
__global__ __launch_bounds__(256) void step_kernel(
    const float* __restrict__ X,
    const int* __restrict__ perm,
    const float* __restrict__ mc,
    const float* __restrict__ mf,
    float* __restrict__ Vst,      // ping-pong [2][CELLS]
    float* __restrict__ Sst,      // ping-pong [2][CELLS]
    float* __restrict__ Achunk,   // [TB][KTOT]
    int t)
{
#pragma clang fp contract(off)
    __shared__ float Sld[20][DD];   // rows y0-8 .. y0+11 of S_{t-1}
    __shared__ float C5[4][DD];     // vertical 5-sums
    __shared__ float C9[4][DD];     // vertical dilated 9-sums
    __shared__ float ut[32];        // tanh of the 32 coarse cells this block touches

    const int tid = threadIdx.x;
    const int y0 = blockIdx.x * 4;  // 4-row strip; stays inside one coarse row
    const int cy = y0 >> 3;

    if (tid < 32) {
        int c = cy * 32 + tid;
        ut[tid] = tanhf(X[(long)t * 1024 + perm[c]] * mc[c]);
    }

    const int rd = (t + 1) & 1, wr = t & 1;
    const float* Sprev = Sst + (long)rd * CELLS;
    for (int i = tid; i < 20 * 64; i += 256) {      // float4 loads: 20 rows * 64 quads
        int rr = i >> 6;
        int x4 = (i & 63) << 2;
        float4 s = make_float4(0.f, 0.f, 0.f, 0.f);
        if (t > 0) {
            int gy = (y0 - 8 + rr) & 255;
            s = *(const float4*)&Sprev[gy * DD + x4];
        }
        *(float4*)&Sld[rr][x4] = s;
    }
    __syncthreads();

    const int x = tid;
#pragma unroll
    for (int ry = 0; ry < 4; ++ry) {
        int r = 8 + ry;
        C5[ry][x] = Sld[r-2][x] + Sld[r-1][x] + Sld[r][x] + Sld[r+1][x] + Sld[r+2][x];
        C9[ry][x] = Sld[r-8][x] + Sld[r-6][x] + Sld[r-4][x] + Sld[r-2][x] + Sld[r][x]
                  + Sld[r+2][x] + Sld[r+4][x] + Sld[r+6][x] + Sld[r+8][x];
    }
    __syncthreads();

    const float* Vprev = Vst + (long)rd * CELLS;
    float* Vout = Vst + (long)wr * CELLS;
    float* Sout = Sst + (long)wr * CELLS;
    float* Arow = Achunk + (long)(t & (TB - 1)) * KTOT;
    const float um = ut[x >> 3];

#pragma unroll
    for (int ry = 0; ry < 4; ++ry) {
        const int y = y0 + ry;
        float h5 = C5[ry][(x-2)&255] + C5[ry][(x-1)&255] + C5[ry][x]
                 + C5[ry][(x+1)&255] + C5[ry][(x+2)&255];
        float h9 = C9[ry][(x-8)&255] + C9[ry][(x-6)&255] + C9[ry][(x-4)&255]
                 + C9[ry][(x-2)&255] + C9[ry][x]
                 + C9[ry][(x+2)&255] + C9[ry][(x+4)&255]
                 + C9[ry][(x+6)&255] + C9[ry][(x+8)&255];
        float avg5 = h5 * (1.0f/25.0f);
        float avg9 = h9 * (1.0f/81.0f);
        float lat = avg5 - 0.5f * avg9;             // EXC*avg5 + INH*avg9
        float u = um * mf[y * DD + x];              // exact: mf in {0,1}
        float Vp = 0.0f;
        if (t > 0) Vp = Vprev[y * DD + x];
        float V1 = 0.9f * Vp + 0.5f * u;            // DECAY*V + SPLIT*x
        float V2 = (V1 >= 0.1f) ? ((V1 + 0.5f * u) + lat) : V1;
        V2 = fminf(V2, 1.0f);
        const bool sp = V2 > 0.75f;
        const float Vn = sp ? 0.0f : V2;
        const float Sn = sp ? 1.0f : 0.0f;
        Vout[y * DD + x] = Vn;
        Sout[y * DD + x] = Sn;
        Arow[y * DD + x] = Vn;
        Arow[CELLS + y * DD + x] = Sn;
    }
}

// Split-K fp32 GEMM on one chunk: 64 t x 128 o x KSLAB k per block. Grid (2, NSLAB).
__global__ __launch_bounds__(256) void gemm_partial(
    const float* __restrict__ A,   // chunk [TB][KTOT]
    const float* __restrict__ B,   // W_out [128][KTOT]
    float* __restrict__ P)         // [NSLAB][TB][128]
{
    __shared__ float As[16][68];   // [k][t]
    __shared__ float Bs[16][132];  // [k][o]
    const int tid = threadIdx.x;
    const int t0 = blockIdx.x * 64;
    const long k0 = (long)blockIdx.y * KSLAB;
    const int tx = tid & 15;       // 8 o's each
    const int ty = tid >> 4;       // 4 t's each

    float acc[4][8];
#pragma unroll
    for (int i = 0; i < 4; ++i)
#pragma unroll
        for (int j = 0; j < 8; ++j) acc[i][j] = 0.0f;

    const int ar = tid >> 2, ac = (tid & 3) * 4;   // A: 64 rows x 16 k
    const int br = tid >> 1, bc = (tid & 1) * 8;   // B: 128 rows x 16 k

    for (int kc = 0; kc < KSLAB; kc += 16) {
        float4 av = *(const float4*)&A[(long)(t0 + ar) * KTOT + k0 + kc + ac];
        As[ac+0][ar] = av.x; As[ac+1][ar] = av.y; As[ac+2][ar] = av.z; As[ac+3][ar] = av.w;
        float4 bv0 = *(const float4*)&B[(long)br * KTOT + k0 + kc + bc];
        float4 bv1 = *(const float4*)&B[(long)br * KTOT + k0 + kc + bc + 4];
        Bs[bc+0][br] = bv0.x; Bs[bc+1][br] = bv0.y; Bs[bc+2][br] = bv0.z; Bs[bc+3][br] = bv0.w;
        Bs[bc+4][br] = bv1.x; Bs[bc+5][br] = bv1.y; Bs[bc+6][br] = bv1.z; Bs[bc+7][br] = bv1.w;
        __syncthreads();
#pragma unroll
        for (int kk = 0; kk < 16; ++kk) {
            float4 a4  = *(const float4*)&As[kk][ty*4];
            float4 b40 = *(const float4*)&Bs[kk][tx*8];
            float4 b41 = *(const float4*)&Bs[kk][tx*8+4];
            float a[4] = {a4.x, a4.y, a4.z, a4.w};
            float b[8] = {b40.x, b40.y, b40.z, b40.w, b41.x, b41.y, b41.z, b41.w};
#pragma unroll
            for (int i = 0; i < 4; ++i)
#pragma unroll
                for (int j = 0; j < 8; ++j) acc[i][j] += a[i] * b[j];
        }
        __syncthreads();
    }
#pragma unroll
    for (int i = 0; i < 4; ++i)
#pragma unroll
        for (int j = 0; j < 8; ++j)
            P[((long)blockIdx.y * TB + t0 + ty*4 + i) * 128 + tx*8 + j] = acc[i][j];
}

// Sum NSLAB partials for one chunk, add bias, write out rows [c*TB, (c+1)*TB).
__global__ __launch_bounds__(256) void reduce_kernel(
    const float* __restrict__ P, const float* __restrict__ bias,
    float* __restrict__ out, int c)
{
    int tid = blockIdx.x * 256 + threadIdx.x;      // 16384 = TB*128
    int o = tid & 127;
    float acc = 0.0f;
#pragma unroll 8
    for (int j = 0; j < NSLAB; ++j) acc += P[(long)j * (TB * 128) + tid];
    out[(long)c * (TB * 128) + tid] = acc + bias[o];
}

} // namespace

extern "C" void kernel_launch(void* const* d_in, const int* in_sizes, int n_in,
                              void* d_out, int out_size, void* d_ws, size_t ws_size,
                              hipStream_t stream)
{
    const float* X  = (const float*)d_in[0];   // [512,1024]
    const float* We = (const float*)d_in[1];   // [1024,1024] permuted identity
    const float* mc = (const float*)d_in[2];   // [32,32]
    const float* mf = (const float*)d_in[3];   // [256,256]
    const float* Wo = (const float*)d_in[4];   // [128,2,256,256]
    const float* bo = (const float*)d_in[5];   // [128]
    float* out = (float*)d_out;                // [512,128] fp32

    if (ws_size < (size_t)WS_REQUIRED) return;  // fail loudly (wrong result, no fault)

    char* ws = (char*)d_ws;
    int*   perm   = (int*)(ws + OFF_PERM);
    float* Vst    = (float*)(ws + OFF_V);
    float* Sst    = (float*)(ws + OFF_S);
    float* Achunk = (float*)(ws + OFF_A);
    float* P      = (float*)(ws + OFF_P);

    perm_kernel<<<4096, 256, 0, stream>>>(We, perm);
    for (int c = 0; c < NCH; ++c) {
        for (int t = c * TB; t < (c + 1) * TB; ++t)
            step_kernel<<<64, 256, 0, stream>>>(X, perm, mc, mf, Vst, Sst, Achunk, t);
        gemm_partial<<<dim3(2, NSLAB), 256, 0, stream>>>(Achunk, Wo, P);
        reduce_kernel<<<64, 256, 0, stream>>>(P, bo, out, c);
    }
}